// Round 12
// baseline (495.401 us; speedup 1.0000x reference)
//
#include <hip/hip_runtime.h>
#include <hip/hip_bf16.h>

typedef __attribute__((ext_vector_type(8))) short bf16x8;
typedef __attribute__((ext_vector_type(8))) unsigned short ushort8;
typedef __attribute__((ext_vector_type(4))) unsigned short ushortx4;
typedef __attribute__((ext_vector_type(4))) float f32x4;

// ---------- helpers ----------
__device__ __forceinline__ unsigned short f2bf(float f) {
  union { float f; unsigned u; } c; c.f = f;
  return (unsigned short)((c.u + 0x7fffu + ((c.u >> 16) & 1u)) >> 16);  // RNE
}
__device__ __forceinline__ float bf2f(unsigned short u) {
  union { unsigned u; float f; } c; c.u = ((unsigned)u) << 16;
  return c.f;
}
__device__ __forceinline__ float fast_tanh(float x) {
  float e = __expf(2.f * x);                       // inf for large x -> rcp->0 -> 1
  return 1.f - 2.f * __builtin_amdgcn_rcpf(e + 1.f);
}
__device__ __forceinline__ float fast_sigmoid(float x) {
  return __builtin_amdgcn_rcpf(1.f + __expf(-x));
}
__device__ __forceinline__ void gload16(const void* g, void* lds) {
  __builtin_amdgcn_global_load_lds(
      (const __attribute__((address_space(1))) unsigned int*)g,
      (__attribute__((address_space(3))) unsigned int*)lds, 16, 0, 0);
}
__device__ __forceinline__ void bar() {
  asm volatile("" ::: "memory");
  __builtin_amdgcn_s_barrier();
  asm volatile("" ::: "memory");
}
__device__ __forceinline__ void vwait0() {
  asm volatile("s_waitcnt vmcnt(0)" ::: "memory");
}
// 8 fp32 -> bf16x8 (RNE; compiler lowers pairs to v_cvt_pk_bf16_f32 per m240)
__device__ __forceinline__ bf16x8 cvt8(f32x4 v0, f32x4 v1) {
  union { bf16x8 v; unsigned short h[8]; } o;
#pragma unroll
  for (int k = 0; k < 4; ++k) {
    o.h[k] = __hip_bfloat16_raw(__float2bfloat16(v0[k])).x;
    o.h[k + 4] = __hip_bfloat16_raw(__float2bfloat16(v1[k])).x;
  }
  return o.v;
}

__device__ __forceinline__ void mfma16_4(const bf16x8 (&a)[4], const bf16x8 (&b)[4],
                                         f32x4 (&acc)[4][4]) {
#pragma unroll
  for (int i = 0; i < 4; ++i)
#pragma unroll
    for (int n = 0; n < 4; ++n)
      acc[i][n] =
          __builtin_amdgcn_mfma_f32_16x16x32_bf16(a[i], b[n], acc[i][n], 0, 0, 0);
}

// ===== shared m97-style 128x128 bf16 core (gemm2): 4 waves, single-buffer =====
// LDS: row l, byte(l,s) = l*128 + ((s^(l&7))*16); staged linear-dest with
// inverse-swizzled global source (rule #21). Wave (wr,wc) owns 64x64 output.
#define GEMM128_SETUP(Ag, Bg)                                                            \
  int lin = (blockIdx.x & 7) * 512 + (blockIdx.x >> 3);                                  \
  int mt = lin >> 3, nt = lin & 7;                                                       \
  int m0 = mt * 128, n0 = nt * 128;                                                      \
  int t = threadIdx.x, lane = t & 63, wave = t >> 6;                                     \
  int wr = wave >> 1, wc = wave & 1;                                                     \
  int sl0 = ((lane >> 4) ^ (lane & 7)) * 16;                                             \
  int sl1 = (((lane >> 4) + 4) ^ (lane & 7)) * 16;                                       \
  const char* rAk0 = (const char*)As + (wr * 64 + (lane & 15)) * 128 + sl0;              \
  const char* rAk1 = (const char*)As + (wr * 64 + (lane & 15)) * 128 + sl1;              \
  const char* rBk0 = (const char*)Bs + (wc * 64 + (lane & 15)) * 128 + sl0;              \
  const char* rBk1 = (const char*)Bs + (wc * 64 + (lane & 15)) * 128 + sl1;              \
  int l3 = t >> 3;                                                                       \
  int sgE = ((t & 7) ^ (l3 & 7)) * 8;                                                    \
  const unsigned short* pA = Ag + (size_t)(m0 + l3) * 1024 + sgE;                        \
  const unsigned short* pB = Bg + (size_t)(n0 + l3) * 1024 + sgE;                        \
  char* dA = (char*)As + t * 16;                                                         \
  char* dB = (char*)Bs + t * 16;                                                         \
  f32x4 acc[4][4] = {};                                                                  \
  _Pragma("unroll 1") for (int kt = 0; kt < 16; ++kt) {                                  \
    int k0 = kt * 64;                                                                    \
    _Pragma("unroll") for (int r = 0; r < 4; ++r) {                                      \
      gload16(pA + (size_t)(r * 32) * 1024 + k0, dA + r * 4096);                         \
      gload16(pB + (size_t)(r * 32) * 1024 + k0, dB + r * 4096);                         \
    }                                                                                    \
    vwait0();                                                                            \
    bar();                                                                               \
    {                                                                                    \
      bf16x8 a[4], b[4];                                                                 \
      _Pragma("unroll") for (int i = 0; i < 4; ++i)                                      \
          a[i] = *(const bf16x8*)(rAk0 + i * 2048);                                      \
      _Pragma("unroll") for (int n = 0; n < 4; ++n)                                      \
          b[n] = *(const bf16x8*)(rBk0 + n * 2048);                                      \
      mfma16_4(a, b, acc);                                                               \
      _Pragma("unroll") for (int i = 0; i < 4; ++i)                                      \
          a[i] = *(const bf16x8*)(rAk1 + i * 2048);                                      \
      _Pragma("unroll") for (int n = 0; n < 4; ++n)                                      \
          b[n] = *(const bf16x8*)(rBk1 + n * 2048);                                      \
      mfma16_4(a, b, acc);                                                               \
    }                                                                                    \
    bar();                                                                               \
  }

// ---------- prep: transpose Wk/Wg (512 blocks) + query partials (32 blocks) ----------
__global__ __launch_bounds__(256) void prep_kernel(
    const float* __restrict__ Wk, const float* __restrict__ Wg,
    unsigned short* __restrict__ WkT, unsigned short* __restrict__ WgT,
    const float* __restrict__ q, const float* __restrict__ Wq,
    float* __restrict__ qp) {
  __shared__ float smem[4160];
  int bid = blockIdx.x, t = threadIdx.x;
  if (bid < 512) {
    int mat = bid >> 8;
    int tid = bid & 255;
    int tr = tid >> 4, tc = tid & 15;
    const float* src = mat ? Wg : Wk;
    unsigned short* dst = mat ? WgT : WkT;
    int r0 = tr * 64, c0 = tc * 64;
    int lr = t >> 6, lc = t & 63;
#pragma unroll
    for (int i = 0; i < 16; ++i) {
      int r = i * 4 + lr;
      smem[r * 65 + lc] = src[(size_t)(r0 + r) * 1024 + c0 + lc];
    }
    __syncthreads();
#pragma unroll
    for (int i = 0; i < 16; ++i) {
      int r = i * 4 + lr;
      dst[(size_t)(c0 + r) * 1024 + r0 + lc] = f2bf(smem[lc * 65 + r]);
    }
  } else {
    // query partials: qp[hc][b][a] = sum_{h in chunk} q[b][h]*Wq[h][a]
    int b3 = bid - 512;            // 32 blocks
    int ac = b3 & 3, hc = b3 >> 2; // 4 a-chunks x 8 h-chunks
    int h0 = hc * 128;
    for (int i = t; i < 4096; i += 256) {
      int b = i >> 7, hh = i & 127;
      smem[b * 128 + hh] = q[(size_t)b * 1024 + h0 + hh];
    }
    __syncthreads();
    int a = ac * 256 + t;
    float acc[32] = {};
    for (int hh = 0; hh < 128; hh += 4) {
      float w0 = Wq[(size_t)(h0 + hh) * 1024 + a];
      float w1 = Wq[(size_t)(h0 + hh + 1) * 1024 + a];
      float w2 = Wq[(size_t)(h0 + hh + 2) * 1024 + a];
      float w3 = Wq[(size_t)(h0 + hh + 3) * 1024 + a];
#pragma unroll
      for (int b = 0; b < 32; ++b) {
        f32x4 qv = *(const f32x4*)&smem[b * 128 + hh];
        acc[b] += qv[0] * w0 + qv[1] * w1 + qv[2] * w2 + qv[3] * w3;
      }
    }
#pragma unroll
    for (int b = 0; b < 32; ++b) qp[((size_t)(hc * 32 + b)) * 1024 + a] = acc[b];
  }
}

// ---------- GEMM1 (128^2, fp32-A direct): align = tanh(seq@WkT^T + query) -> bf16 ----------
// A staged as fp32 in LDS (32 KB, 16 slots/row, phys = logical ^ (l&15)); converted
// to bf16 on the fragment read. B bf16 as in GEMM128_SETUP. 48 KB LDS -> 3 blk/CU.
__global__ __launch_bounds__(256, 2) void gemm1_kernel(
    const float* __restrict__ seq, const unsigned short* __restrict__ WkT,
    const float* __restrict__ qp, const float* __restrict__ bq,
    const float* __restrict__ bk, unsigned short* __restrict__ alignb) {
  __shared__ float As[128 * 64];           // fp32 A tile, 32 KB
  __shared__ unsigned short Bs[128 * 64];  // bf16 B tile, 16 KB
  int lin = (blockIdx.x & 7) * 512 + (blockIdx.x >> 3);
  int mt = lin >> 3, nt = lin & 7;
  int m0 = mt * 128, n0 = nt * 128;
  int t = threadIdx.x, lane = t & 63, wave = t >> 6;
  int wr = wave >> 1, wc = wave & 1;
  int l15 = lane & 15, g = lane >> 4;
  // B read bases (bf16, 8 slots, XOR l&7)
  int sl0 = (g ^ (lane & 7)) * 16;
  int sl1 = ((g + 4) ^ (lane & 7)) * 16;
  const char* rBk0 = (const char*)Bs + (wc * 64 + l15) * 128 + sl0;
  const char* rBk1 = (const char*)Bs + (wc * 64 + l15) * 128 + sl1;
  // A read bases (fp32, 16 slots, XOR l&15). Logical slots: kk*8 + 2g (+1).
  // Row l = wr*64 + i*16 + l15 -> (l&15) = l15; row stride i -> +4096 B.
  const char* aRow = (const char*)As + (wr * 64 + l15) * 256;
  const char* rA00 = aRow + (((2 * g) ^ l15) * 16);
  const char* rA01 = aRow + ((((2 * g) | 1) ^ l15) * 16);
  const char* rA10 = aRow + ((((2 * g) ^ 8) ^ l15) * 16);
  const char* rA11 = aRow + (((((2 * g) | 1) ^ 8) ^ l15) * 16);
  // A staging: 8 chunks/thread; chunk c = r*256+t -> row l = r*16+(t>>4), phys p = t&15;
  // src col = 4*(p ^ (l&15)) = 4*((t&15)^(t>>4)) -- constant per thread.
  int sgA = ((t & 15) ^ (t >> 4)) * 4;
  const float* pAf = seq + (size_t)(m0 + (t >> 4)) * 1024 + sgA;
  // B staging (bf16): 4 chunks/thread
  int l3 = t >> 3;
  int sgE = ((t & 7) ^ (l3 & 7)) * 8;
  const unsigned short* pB = WkT + (size_t)(n0 + l3) * 1024 + sgE;
  char* dA = (char*)As + t * 16;
  char* dB = (char*)Bs + t * 16;
  f32x4 acc[4][4] = {};
#pragma unroll 1
  for (int kt = 0; kt < 16; ++kt) {
    int k0 = kt * 64;
#pragma unroll
    for (int r = 0; r < 8; ++r)
      gload16(pAf + (size_t)(r * 16) * 1024 + k0, dA + r * 4096);
#pragma unroll
    for (int r = 0; r < 4; ++r)
      gload16(pB + (size_t)(r * 32) * 1024 + k0, dB + r * 4096);
    vwait0();
    bar();
    {
      bf16x8 a[4], b[4];
#pragma unroll
      for (int i = 0; i < 4; ++i)
        a[i] = cvt8(*(const f32x4*)(rA00 + i * 4096), *(const f32x4*)(rA01 + i * 4096));
#pragma unroll
      for (int n = 0; n < 4; ++n) b[n] = *(const bf16x8*)(rBk0 + n * 2048);
      mfma16_4(a, b, acc);
#pragma unroll
      for (int i = 0; i < 4; ++i)
        a[i] = cvt8(*(const f32x4*)(rA10 + i * 4096), *(const f32x4*)(rA11 + i * 4096));
#pragma unroll
      for (int n = 0; n < 4; ++n) b[n] = *(const bf16x8*)(rBk1 + n * 2048);
      mfma16_4(a, b, acc);
    }
    bar();
  }

  // epilogue: fold query reduce (8 partials + bq + bk), tanh, store bf16
  int bidx = m0 >> 11;  // 128-row tile stays in one batch (2048 % 128 == 0)
  float qv[4];
#pragma unroll
  for (int ni = 0; ni < 4; ++ni) {
    int col = n0 + wc * 64 + ni * 16 + l15;
    float s = bq[col] + bk[col];
#pragma unroll
    for (int hc = 0; hc < 8; ++hc) s += qp[((size_t)(hc * 32 + bidx)) * 1024 + col];
    qv[ni] = s;
  }
#pragma unroll
  for (int mi = 0; mi < 4; ++mi) {
    int row0 = m0 + wr * 64 + mi * 16 + ((lane >> 4) * 4);
#pragma unroll
    for (int ni = 0; ni < 4; ++ni) {
      int col = n0 + wc * 64 + ni * 16 + l15;
#pragma unroll
      for (int j = 0; j < 4; ++j) {
        float v = fast_tanh(acc[mi][ni][j] + qv[ni]);
        alignb[(size_t)(row0 + j) * 1024 + col] = f2bf(v);
      }
    }
  }
}

// ---------- GEMM2 (128^2): scores_part[nt,row] = sum_col align*sigmoid(align@Wg+bg)*Ws ----------
__global__ __launch_bounds__(256, 2) void gemm2_kernel(
    const unsigned short* __restrict__ alignb, const unsigned short* __restrict__ WgT,
    const float* __restrict__ bg, const float* __restrict__ Ws,
    float* __restrict__ scores_part) {
  __shared__ unsigned short As[128 * 64];
  __shared__ unsigned short Bs[128 * 64];
  __shared__ float sred[128 * 2];
  GEMM128_SETUP(alignb, WgT)

  // epilogue: gate + weighted row-reduction
#pragma unroll
  for (int mi = 0; mi < 4; ++mi) {
#pragma unroll
    for (int j = 0; j < 4; ++j) {
      int rloc = wr * 64 + mi * 16 + ((lane >> 4) * 4) + j;
      int row = m0 + rloc;
      float p = 0.f;
#pragma unroll
      for (int ni = 0; ni < 4; ++ni) {
        int col = n0 + wc * 64 + ni * 16 + (lane & 15);
        float gate = fast_sigmoid(acc[mi][ni][j] + bg[col]);
        float al = bf2f(alignb[(size_t)row * 1024 + col]);
        p += al * gate * Ws[col];
      }
      p += __shfl_xor(p, 1);
      p += __shfl_xor(p, 2);
      p += __shfl_xor(p, 4);
      p += __shfl_xor(p, 8);
      if ((lane & 15) == 0) sred[rloc * 2 + wc] = p;
    }
  }
  __syncthreads();
  if (t < 128) scores_part[(size_t)nt * 65536 + m0 + t] = sred[t * 2] + sred[t * 2 + 1];
}

// ---------- softmax over S=2048 per batch (8 partials); writes weights output ----------
__global__ __launch_bounds__(256) void softmax_kernel(const float* __restrict__ sp,
                                                      float* __restrict__ wout) {
  __shared__ float red[256];
  int b = blockIdx.x, t = threadIdx.x;
  float sc[8];
  float lmax = -1e30f;
#pragma unroll
  for (int i = 0; i < 8; ++i) {
    int s = i * 256 + t;
    float v = 0.f;
#pragma unroll
    for (int n = 0; n < 8; ++n) v += sp[(size_t)n * 65536 + b * 2048 + s];
    sc[i] = v;
    lmax = fmaxf(lmax, v);
  }
  red[t] = lmax;
  __syncthreads();
  for (int off = 128; off > 0; off >>= 1) {
    if (t < off) red[t] = fmaxf(red[t], red[t + off]);
    __syncthreads();
  }
  float mx = red[0];
  __syncthreads();
  float lsum = 0.f;
#pragma unroll
  for (int i = 0; i < 8; ++i) {
    sc[i] = expf(sc[i] - mx);
    lsum += sc[i];
  }
  red[t] = lsum;
  __syncthreads();
  for (int off = 128; off > 0; off >>= 1) {
    if (t < off) red[t] += red[t + off];
    __syncthreads();
  }
  float inv = 1.f / red[0];
#pragma unroll
  for (int i = 0; i < 8; ++i) wout[(size_t)b * 2048 + i * 256 + t] = sc[i] * inv;
}

// ---------- context partials (fp32 seq read, 4 h per thread, 16 s-chunks) ----------
__global__ __launch_bounds__(256) void context_kernel(const float* __restrict__ seq,
                                                      const float* __restrict__ wts,
                                                      float* __restrict__ ctx_part) {
  __shared__ float wsh[128];
  int b = blockIdx.x, t = threadIdx.x, s0 = blockIdx.z * 128;
  int h0 = t * 4;
  if (t < 128) wsh[t] = wts[(size_t)b * 2048 + s0 + t];
  __syncthreads();
  float a0 = 0.f, a1 = 0.f, a2 = 0.f, a3 = 0.f;
  const float* p = seq + ((size_t)b * 2048 + s0) * 1024 + h0;
#pragma unroll 4
  for (int s = 0; s < 128; ++s) {
    f32x4 v = *(const f32x4*)(p + (size_t)s * 1024);
    float w = wsh[s];
    a0 += w * v[0];
    a1 += w * v[1];
    a2 += w * v[2];
    a3 += w * v[3];
  }
  float* dst = ctx_part + (size_t)(blockIdx.z * 32 + b) * 1024 + h0;
  dst[0] = a0; dst[1] = a1; dst[2] = a2; dst[3] = a3;
}

// ---------- pre partials: Wo read ONCE. grid (16 k-chunks of 128, 4 h-chunks) ----------
__global__ __launch_bounds__(256) void pre_kernel(const float* __restrict__ ctx_part,
                                                  const float* __restrict__ q,
                                                  const float* __restrict__ Wo,
                                                  float* __restrict__ pre_part) {
  __shared__ float fin[32 * 128];
  int kc = blockIdx.x, hc = blockIdx.y, t = threadIdx.x;
  int k0 = kc * 128, h0 = hc * 256;
  for (int i = t; i < 4096; i += 256) {
    int b = i >> 7, kk = i & 127, k = k0 + kk;
    float f;
    if (k < 1024) {
      f = 0.f;
#pragma unroll
      for (int s = 0; s < 16; ++s) f += ctx_part[((size_t)(s * 32 + b)) * 1024 + k];
    } else {
      f = q[(size_t)b * 1024 + (k - 1024)];
    }
    fin[b * 128 + kk] = f;
  }
  __syncthreads();
  int h = h0 + t;
  float acc[32] = {};
  for (int kk = 0; kk < 128; kk += 4) {
    float w0 = Wo[(size_t)(k0 + kk) * 1024 + h];
    float w1 = Wo[(size_t)(k0 + kk + 1) * 1024 + h];
    float w2 = Wo[(size_t)(k0 + kk + 2) * 1024 + h];
    float w3 = Wo[(size_t)(k0 + kk + 3) * 1024 + h];
#pragma unroll
    for (int b = 0; b < 32; ++b) {
      f32x4 fv = *(const f32x4*)&fin[b * 128 + kk];
      acc[b] += fv[0] * w0 + fv[1] * w1 + fv[2] * w2 + fv[3] * w3;
    }
  }
#pragma unroll
  for (int b = 0; b < 32; ++b) pre_part[((size_t)(kc * 32 + b)) * 1024 + h] = acc[b];
}

// ---------- final: residual + layernorm ----------
__global__ __launch_bounds__(256) void ln_kernel(const float* __restrict__ pre_part,
                                                 const float* __restrict__ q,
                                                 const float* __restrict__ bo,
                                                 const float* __restrict__ gamma,
                                                 const float* __restrict__ beta,
                                                 float* __restrict__ outF) {
  __shared__ float red[256];
  int b = blockIdx.x, t = threadIdx.x;
  float v[4];
  float lsum = 0.f;
#pragma unroll
  for (int i = 0; i < 4; ++i) {
    int h = i * 256 + t;
    float x = bo[h] + q[(size_t)b * 1024 + h];
#pragma unroll
    for (int kc = 0; kc < 16; ++kc) x += pre_part[((size_t)(kc * 32 + b)) * 1024 + h];
    v[i] = x;
    lsum += x;
  }
  red[t] = lsum;
  __syncthreads();
  for (int off = 128; off > 0; off >>= 1) {
    if (t < off) red[t] += red[t + off];
    __syncthreads();
  }
  float mu = red[0] * (1.f / 1024.f);
  __syncthreads();
  float lv = 0.f;
#pragma unroll
  for (int i = 0; i < 4; ++i) {
    float d = v[i] - mu;
    lv += d * d;
  }
  red[t] = lv;
  __syncthreads();
  for (int off = 128; off > 0; off >>= 1) {
    if (t < off) red[t] += red[t + off];
    __syncthreads();
  }
  float var = red[0] * (1.f / 1024.f);
  float rs = rsqrtf(var + 1e-5f);
#pragma unroll
  for (int i = 0; i < 4; ++i) {
    int h = i * 256 + t;
    outF[(size_t)b * 1024 + h] = (v[i] - mu) * rs * gamma[h] + beta[h];
  }
}

// ---------- host ----------
extern "C" void kernel_launch(void* const* d_in, const int* in_sizes, int n_in,
                              void* d_out, int out_size, void* d_ws, size_t ws_size,
                              hipStream_t stream) {
  const float* seq = (const float*)d_in[0];
  const float* q = (const float*)d_in[1];
  const float* Wk = (const float*)d_in[2];
  const float* bk = (const float*)d_in[3];
  const float* Wq = (const float*)d_in[4];
  const float* bq = (const float*)d_in[5];
  const float* Wg = (const float*)d_in[6];
  const float* bg = (const float*)d_in[7];
  const float* Ws = (const float*)d_in[8];
  // d_in[9] = bs: softmax is shift-invariant, cancels everywhere it appears
  const float* Wo = (const float*)d_in[10];
  const float* bo = (const float*)d_in[11];
  const float* gamma = (const float*)d_in[12];
  const float* beta = (const float*)d_in[13];

  float* outF = (float*)d_out;         // fused [32,1024]
  float* outW = outF + 32 * 1024;      // weights [32,2048]

  char* ws = (char*)d_ws;
  unsigned short* alignb = (unsigned short*)ws;  ws += (size_t)134217728;  // [65536,1024] bf16
  unsigned short* WkT = (unsigned short*)ws;     ws += 2097152;            // [1024,1024] bf16
  unsigned short* WgT = (unsigned short*)ws;     ws += 2097152;
  float* qp = (float*)ws;                        ws += 1048576;            // [8,32,1024]
  float* scores_part = (float*)ws;               ws += 2097152;            // [8,65536]
  float* ctx_part = (float*)ws;                  ws += 2097152;            // [16,32,1024]
  float* pre_part = (float*)ws;                  ws += 2097152;            // [16,32,1024]
  if (ws_size < (size_t)(ws - (char*)d_ws)) return;  // insufficient scratch

  prep_kernel<<<544, 256, 0, stream>>>(Wk, Wg, WkT, WgT, q, Wq, qp);
  gemm1_kernel<<<4096, 256, 0, stream>>>(seq, WkT, qp, bq, bk, alignb);
  gemm2_kernel<<<4096, 256, 0, stream>>>(alignb, WgT, bg, Ws, scores_part);
  softmax_kernel<<<32, 256, 0, stream>>>(scores_part, outW);
  context_kernel<<<dim3(32, 1, 16), 256, 0, stream>>>(seq, outW, ctx_part);
  pre_kernel<<<dim3(16, 4), 256, 0, stream>>>(ctx_part, q, Wo, pre_part);
  ln_kernel<<<32, 256, 0, stream>>>(pre_part, q, bo, gamma, beta, outF);
}

// Round 13
// 482.624 us; speedup vs baseline: 1.0265x; 1.0265x over previous
//
#include <hip/hip_runtime.h>

typedef __attribute__((ext_vector_type(8))) short bf16x8;
typedef __attribute__((ext_vector_type(8))) unsigned short ushort8;
typedef __attribute__((ext_vector_type(4))) unsigned short ushortx4;
typedef __attribute__((ext_vector_type(4))) float f32x4;

// ---------- helpers ----------
__device__ __forceinline__ unsigned short f2bf(float f) {
  union { float f; unsigned u; } c; c.f = f;
  return (unsigned short)((c.u + 0x7fffu + ((c.u >> 16) & 1u)) >> 16);  // RNE
}
__device__ __forceinline__ float bf2f(unsigned short u) {
  union { unsigned u; float f; } c; c.u = ((unsigned)u) << 16;
  return c.f;
}
__device__ __forceinline__ float fast_tanh(float x) {
  float e = __expf(2.f * x);                       // inf for large x -> rcp->0 -> 1
  return 1.f - 2.f * __builtin_amdgcn_rcpf(e + 1.f);
}
__device__ __forceinline__ float fast_sigmoid(float x) {
  return __builtin_amdgcn_rcpf(1.f + __expf(-x));
}
__device__ __forceinline__ void gload16(const void* g, void* lds) {
  __builtin_amdgcn_global_load_lds(
      (const __attribute__((address_space(1))) unsigned int*)g,
      (__attribute__((address_space(3))) unsigned int*)lds, 16, 0, 0);
}
__device__ __forceinline__ void bar() {
  asm volatile("" ::: "memory");
  __builtin_amdgcn_s_barrier();
  asm volatile("" ::: "memory");
}
__device__ __forceinline__ void vwait0() {
  asm volatile("s_waitcnt vmcnt(0)" ::: "memory");
}

__device__ __forceinline__ void mfma16_4(const bf16x8 (&a)[4], const bf16x8 (&b)[4],
                                         f32x4 (&acc)[4][4]) {
#pragma unroll
  for (int i = 0; i < 4; ++i)
#pragma unroll
    for (int n = 0; n < 4; ++n)
      acc[i][n] =
          __builtin_amdgcn_mfma_f32_16x16x32_bf16(a[i], b[n], acc[i][n], 0, 0, 0);
}

// ===== shared m97-style 128x128 core: 4 waves, single-buffer, 2 bars/K-tile =====
// LDS layout: row l, byte(l,s) = l*128 + ((s^(l&7))*16); staged linear-dest with
// inverse-swizzled global source (rule #21). Wave (wr,wc) owns 64x64 output.
// This is the verified K=1024 local optimum (r10-r12 A/B: beats five 256^2
// deep-pipelined schedules and fp32-A staging, which is stage-volume-bound).
#define GEMM128_SETUP(Ag, Bg)                                                            \
  int lin = (blockIdx.x & 7) * 512 + (blockIdx.x >> 3);                                  \
  int mt = lin >> 3, nt = lin & 7;                                                       \
  int m0 = mt * 128, n0 = nt * 128;                                                      \
  int t = threadIdx.x, lane = t & 63, wave = t >> 6;                                     \
  int wr = wave >> 1, wc = wave & 1;                                                     \
  int sl0 = ((lane >> 4) ^ (lane & 7)) * 16;                                             \
  int sl1 = (((lane >> 4) + 4) ^ (lane & 7)) * 16;                                       \
  const char* rAk0 = (const char*)As + (wr * 64 + (lane & 15)) * 128 + sl0;              \
  const char* rAk1 = (const char*)As + (wr * 64 + (lane & 15)) * 128 + sl1;              \
  const char* rBk0 = (const char*)Bs + (wc * 64 + (lane & 15)) * 128 + sl0;              \
  const char* rBk1 = (const char*)Bs + (wc * 64 + (lane & 15)) * 128 + sl1;              \
  int l3 = t >> 3;                                                                       \
  int sgE = ((t & 7) ^ (l3 & 7)) * 8;                                                    \
  const unsigned short* pA = Ag + (size_t)(m0 + l3) * 1024 + sgE;                        \
  const unsigned short* pB = Bg + (size_t)(n0 + l3) * 1024 + sgE;                        \
  char* dA = (char*)As + t * 16;                                                         \
  char* dB = (char*)Bs + t * 16;                                                         \
  f32x4 acc[4][4] = {};                                                                  \
  _Pragma("unroll 1") for (int kt = 0; kt < 16; ++kt) {                                  \
    int k0 = kt * 64;                                                                    \
    _Pragma("unroll") for (int r = 0; r < 4; ++r) {                                      \
      gload16(pA + (size_t)(r * 32) * 1024 + k0, dA + r * 4096);                         \
      gload16(pB + (size_t)(r * 32) * 1024 + k0, dB + r * 4096);                         \
    }                                                                                    \
    vwait0();                                                                            \
    bar();                                                                               \
    {                                                                                    \
      bf16x8 a[4], b[4];                                                                 \
      _Pragma("unroll") for (int i = 0; i < 4; ++i)                                      \
          a[i] = *(const bf16x8*)(rAk0 + i * 2048);                                      \
      _Pragma("unroll") for (int n = 0; n < 4; ++n)                                      \
          b[n] = *(const bf16x8*)(rBk0 + n * 2048);                                      \
      mfma16_4(a, b, acc);                                                               \
      _Pragma("unroll") for (int i = 0; i < 4; ++i)                                      \
          a[i] = *(const bf16x8*)(rAk1 + i * 2048);                                      \
      _Pragma("unroll") for (int n = 0; n < 4; ++n)                                      \
          b[n] = *(const bf16x8*)(rBk1 + n * 2048);                                      \
      mfma16_4(a, b, acc);                                                               \
    }                                                                                    \
    bar();                                                                               \
  }

// ---------- prep: convert (2048 blocks) + transpose (512) + query partials (32) ----------
__global__ __launch_bounds__(256) void prep_kernel(
    const float* __restrict__ seq, unsigned short* __restrict__ seqb,
    const float* __restrict__ Wk, const float* __restrict__ Wg,
    unsigned short* __restrict__ WkT, unsigned short* __restrict__ WgT,
    const float* __restrict__ q, const float* __restrict__ Wq,
    float* __restrict__ qp) {
  __shared__ float smem[4160];
  int bid = blockIdx.x, t = threadIdx.x;
  if (bid < 2048) {
    size_t i = ((size_t)bid * 256 + t) * 8;
    const size_t stride = (size_t)2048 * 256 * 8;
    for (; i < (size_t)67108864; i += stride) {
      f32x4 v0 = *(const f32x4*)(seq + i);
      f32x4 v1 = *(const f32x4*)(seq + i + 4);
      ushort8 o;
#pragma unroll
      for (int k = 0; k < 4; ++k) { o[k] = f2bf(v0[k]); o[k + 4] = f2bf(v1[k]); }
      *(ushort8*)(seqb + i) = o;
    }
  } else if (bid < 2560) {
    int b2 = bid - 2048;
    int mat = b2 >> 8;
    int tid = b2 & 255;
    int tr = tid >> 4, tc = tid & 15;
    const float* src = mat ? Wg : Wk;
    unsigned short* dst = mat ? WgT : WkT;
    int r0 = tr * 64, c0 = tc * 64;
    int lr = t >> 6, lc = t & 63;
#pragma unroll
    for (int i = 0; i < 16; ++i) {
      int r = i * 4 + lr;
      smem[r * 65 + lc] = src[(size_t)(r0 + r) * 1024 + c0 + lc];
    }
    __syncthreads();
#pragma unroll
    for (int i = 0; i < 16; ++i) {
      int r = i * 4 + lr;
      dst[(size_t)(c0 + r) * 1024 + r0 + lc] = f2bf(smem[lc * 65 + r]);
    }
  } else {
    // query partials: qp[hc][b][a] = sum_{h in chunk} q[b][h]*Wq[h][a]
    int b3 = bid - 2560;           // 32 blocks
    int ac = b3 & 3, hc = b3 >> 2; // 4 a-chunks x 8 h-chunks
    int h0 = hc * 128;
    for (int i = t; i < 4096; i += 256) {
      int b = i >> 7, hh = i & 127;
      smem[b * 128 + hh] = q[(size_t)b * 1024 + h0 + hh];
    }
    __syncthreads();
    int a = ac * 256 + t;
    float acc[32] = {};
    for (int hh = 0; hh < 128; hh += 4) {
      float w0 = Wq[(size_t)(h0 + hh) * 1024 + a];
      float w1 = Wq[(size_t)(h0 + hh + 1) * 1024 + a];
      float w2 = Wq[(size_t)(h0 + hh + 2) * 1024 + a];
      float w3 = Wq[(size_t)(h0 + hh + 3) * 1024 + a];
#pragma unroll
      for (int b = 0; b < 32; ++b) {
        f32x4 qv = *(const f32x4*)&smem[b * 128 + hh];
        acc[b] += qv[0] * w0 + qv[1] * w1 + qv[2] * w2 + qv[3] * w3;
      }
    }
#pragma unroll
    for (int b = 0; b < 32; ++b) qp[((size_t)(hc * 32 + b)) * 1024 + a] = acc[b];
  }
}

// ---------- GEMM1 (128^2): align = tanh(seqb@WkT^T + query) -> bf16 ----------
__global__ __launch_bounds__(256, 2) void gemm1_kernel(
    const unsigned short* __restrict__ seqb, const unsigned short* __restrict__ WkT,
    const float* __restrict__ qp, const float* __restrict__ bq,
    const float* __restrict__ bk, unsigned short* __restrict__ alignb) {
  __shared__ unsigned short As[128 * 64];
  __shared__ unsigned short Bs[128 * 64];
  GEMM128_SETUP(seqb, WkT)

  // epilogue: fold query reduce (8 partials + bq + bk), tanh, store bf16
  int bidx = m0 >> 11;  // 128-row tile stays in one batch (2048 % 128 == 0)
  float qv[4];
#pragma unroll
  for (int ni = 0; ni < 4; ++ni) {
    int col = n0 + wc * 64 + ni * 16 + (lane & 15);
    float s = bq[col] + bk[col];
#pragma unroll
    for (int hc = 0; hc < 8; ++hc) s += qp[((size_t)(hc * 32 + bidx)) * 1024 + col];
    qv[ni] = s;
  }
#pragma unroll
  for (int mi = 0; mi < 4; ++mi) {
    int row0 = m0 + wr * 64 + mi * 16 + ((lane >> 4) * 4);
#pragma unroll
    for (int ni = 0; ni < 4; ++ni) {
      int col = n0 + wc * 64 + ni * 16 + (lane & 15);
#pragma unroll
      for (int j = 0; j < 4; ++j) {
        float v = fast_tanh(acc[mi][ni][j] + qv[ni]);
        alignb[(size_t)(row0 + j) * 1024 + col] = f2bf(v);
      }
    }
  }
}

// ---------- GEMM2 (128^2): scores_part[nt,row] = sum_col align*sigmoid(align@Wg+bg)*Ws ----------
__global__ __launch_bounds__(256, 2) void gemm2_kernel(
    const unsigned short* __restrict__ alignb, const unsigned short* __restrict__ WgT,
    const float* __restrict__ bg, const float* __restrict__ Ws,
    float* __restrict__ scores_part) {
  __shared__ unsigned short As[128 * 64];
  __shared__ unsigned short Bs[128 * 64];
  __shared__ float sred[128 * 2];
  GEMM128_SETUP(alignb, WgT)

  // epilogue: gate + weighted row-reduction
#pragma unroll
  for (int mi = 0; mi < 4; ++mi) {
#pragma unroll
    for (int j = 0; j < 4; ++j) {
      int rloc = wr * 64 + mi * 16 + ((lane >> 4) * 4) + j;
      int row = m0 + rloc;
      float p = 0.f;
#pragma unroll
      for (int ni = 0; ni < 4; ++ni) {
        int col = n0 + wc * 64 + ni * 16 + (lane & 15);
        float gate = fast_sigmoid(acc[mi][ni][j] + bg[col]);
        float al = bf2f(alignb[(size_t)row * 1024 + col]);
        p += al * gate * Ws[col];
      }
      p += __shfl_xor(p, 1);
      p += __shfl_xor(p, 2);
      p += __shfl_xor(p, 4);
      p += __shfl_xor(p, 8);
      if ((lane & 15) == 0) sred[rloc * 2 + wc] = p;
    }
  }
  __syncthreads();
  if (t < 128) scores_part[(size_t)nt * 65536 + m0 + t] = sred[t * 2] + sred[t * 2 + 1];
}

// ---------- context + fused softmax ----------
// Each block (b, z): reduce the 8 score-partials for batch b (fixed order ->
// deterministic, identical across blocks), softmax, write its disjoint 128-wide
// slice of the weights output, then compute its context partial from seqb.
__global__ __launch_bounds__(256) void context_kernel(const unsigned short* __restrict__ seqb,
                                                      const float* __restrict__ sp,
                                                      float* __restrict__ wout,
                                                      float* __restrict__ ctx_part) {
  __shared__ float wsh[128];
  __shared__ float red[256];
  int b = blockIdx.x, t = threadIdx.x, z = blockIdx.z;
  int s0 = z * 128;
  // scores for batch b: thread t holds s = i*256 + t
  const float* spb = sp + (size_t)b * 2048;
  float sc[8];
  float lmax = -1e30f;
#pragma unroll
  for (int i = 0; i < 8; ++i) {
    int s = i * 256 + t;
    float v = 0.f;
#pragma unroll
    for (int n = 0; n < 8; ++n) v += spb[(size_t)n * 65536 + s];
    sc[i] = v;
    lmax = fmaxf(lmax, v);
  }
  red[t] = lmax;
  __syncthreads();
  for (int off = 128; off > 0; off >>= 1) {
    if (t < off) red[t] = fmaxf(red[t], red[t + off]);
    __syncthreads();
  }
  float mx = red[0];
  __syncthreads();
  float lsum = 0.f;
#pragma unroll
  for (int i = 0; i < 8; ++i) {
    sc[i] = expf(sc[i] - mx);
    lsum += sc[i];
  }
  red[t] = lsum;
  __syncthreads();
  for (int off = 128; off > 0; off >>= 1) {
    if (t < off) red[t] += red[t + off];
    __syncthreads();
  }
  float inv = 1.f / red[0];
  // this block's slice [s0, s0+128) = chunk i0 = z>>1, thread range toff..toff+127
  int i0 = z >> 1, toff = (z & 1) * 128;
  int tl = t - toff;
  if (tl >= 0 && tl < 128) {
    float w = sc[i0] * inv;
    wsh[tl] = w;
    wout[(size_t)b * 2048 + s0 + tl] = w;
  }
  __syncthreads();
  // context partial over this s-slice
  int h0 = t * 4;
  float a0 = 0.f, a1 = 0.f, a2 = 0.f, a3 = 0.f;
  const unsigned short* p = seqb + ((size_t)b * 2048 + s0) * 1024 + h0;
#pragma unroll 4
  for (int s = 0; s < 128; ++s) {
    ushortx4 v = *(const ushortx4*)(p + (size_t)s * 1024);
    float w = wsh[s];
    a0 += w * bf2f(v[0]);
    a1 += w * bf2f(v[1]);
    a2 += w * bf2f(v[2]);
    a3 += w * bf2f(v[3]);
  }
  float* dst = ctx_part + (size_t)(z * 32 + b) * 1024 + h0;
  dst[0] = a0; dst[1] = a1; dst[2] = a2; dst[3] = a3;
}

// ---------- pre partials: Wo read ONCE. grid (16 k-chunks of 128, 4 h-chunks) ----------
__global__ __launch_bounds__(256) void pre_kernel(const float* __restrict__ ctx_part,
                                                  const float* __restrict__ q,
                                                  const float* __restrict__ Wo,
                                                  float* __restrict__ pre_part) {
  __shared__ float fin[32 * 128];
  int kc = blockIdx.x, hc = blockIdx.y, t = threadIdx.x;
  int k0 = kc * 128, h0 = hc * 256;
  for (int i = t; i < 4096; i += 256) {
    int b = i >> 7, kk = i & 127, k = k0 + kk;
    float f;
    if (k < 1024) {
      f = 0.f;
#pragma unroll
      for (int s = 0; s < 16; ++s) f += ctx_part[((size_t)(s * 32 + b)) * 1024 + k];
    } else {
      f = q[(size_t)b * 1024 + (k - 1024)];
    }
    fin[b * 128 + kk] = f;
  }
  __syncthreads();
  int h = h0 + t;
  float acc[32] = {};
  for (int kk = 0; kk < 128; kk += 4) {
    float w0 = Wo[(size_t)(k0 + kk) * 1024 + h];
    float w1 = Wo[(size_t)(k0 + kk + 1) * 1024 + h];
    float w2 = Wo[(size_t)(k0 + kk + 2) * 1024 + h];
    float w3 = Wo[(size_t)(k0 + kk + 3) * 1024 + h];
#pragma unroll
    for (int b = 0; b < 32; ++b) {
      f32x4 fv = *(const f32x4*)&fin[b * 128 + kk];
      acc[b] += fv[0] * w0 + fv[1] * w1 + fv[2] * w2 + fv[3] * w3;
    }
  }
#pragma unroll
  for (int b = 0; b < 32; ++b) pre_part[((size_t)(kc * 32 + b)) * 1024 + h] = acc[b];
}

// ---------- final: residual + layernorm ----------
__global__ __launch_bounds__(256) void ln_kernel(const float* __restrict__ pre_part,
                                                 const float* __restrict__ q,
                                                 const float* __restrict__ bo,
                                                 const float* __restrict__ gamma,
                                                 const float* __restrict__ beta,
                                                 float* __restrict__ outF) {
  __shared__ float red[256];
  int b = blockIdx.x, t = threadIdx.x;
  float v[4];
  float lsum = 0.f;
#pragma unroll
  for (int i = 0; i < 4; ++i) {
    int h = i * 256 + t;
    float x = bo[h] + q[(size_t)b * 1024 + h];
#pragma unroll
    for (int kc = 0; kc < 16; ++kc) x += pre_part[((size_t)(kc * 32 + b)) * 1024 + h];
    v[i] = x;
    lsum += x;
  }
  red[t] = lsum;
  __syncthreads();
  for (int off = 128; off > 0; off >>= 1) {
    if (t < off) red[t] += red[t + off];
    __syncthreads();
  }
  float mu = red[0] * (1.f / 1024.f);
  __syncthreads();
  float lv = 0.f;
#pragma unroll
  for (int i = 0; i < 4; ++i) {
    float d = v[i] - mu;
    lv += d * d;
  }
  red[t] = lv;
  __syncthreads();
  for (int off = 128; off > 0; off >>= 1) {
    if (t < off) red[t] += red[t + off];
    __syncthreads();
  }
  float var = red[0] * (1.f / 1024.f);
  float rs = rsqrtf(var + 1e-5f);
#pragma unroll
  for (int i = 0; i < 4; ++i) {
    int h = i * 256 + t;
    outF[(size_t)b * 1024 + h] = (v[i] - mu) * rs * gamma[h] + beta[h];
  }
}

// ---------- host ----------
extern "C" void kernel_launch(void* const* d_in, const int* in_sizes, int n_in,
                              void* d_out, int out_size, void* d_ws, size_t ws_size,
                              hipStream_t stream) {
  const float* seq = (const float*)d_in[0];
  const float* q = (const float*)d_in[1];
  const float* Wk = (const float*)d_in[2];
  const float* bk = (const float*)d_in[3];
  const float* Wq = (const float*)d_in[4];
  const float* bq = (const float*)d_in[5];
  const float* Wg = (const float*)d_in[6];
  const float* bg = (const float*)d_in[7];
  const float* Ws = (const float*)d_in[8];
  // d_in[9] = bs: softmax is shift-invariant, cancels everywhere it appears
  const float* Wo = (const float*)d_in[10];
  const float* bo = (const float*)d_in[11];
  const float* gamma = (const float*)d_in[12];
  const float* beta = (const float*)d_in[13];

  float* outF = (float*)d_out;         // fused [32,1024]
  float* outW = outF + 32 * 1024;      // weights [32,2048]

  char* ws = (char*)d_ws;
  unsigned short* alignb = (unsigned short*)ws;  ws += (size_t)134217728;  // [65536,1024] bf16
  unsigned short* seqb = (unsigned short*)ws;    ws += (size_t)134217728;  // [65536,1024] bf16
  unsigned short* WkT = (unsigned short*)ws;     ws += 2097152;            // [1024,1024] bf16
  unsigned short* WgT = (unsigned short*)ws;     ws += 2097152;
  float* qp = (float*)ws;                        ws += 1048576;            // [8,32,1024]
  float* scores_part = (float*)ws;               ws += 2097152;            // [8,65536]
  float* ctx_part = (float*)ws;                  ws += 2097152;            // [16,32,1024]
  float* pre_part = (float*)ws;                  ws += 2097152;            // [16,32,1024]
  if (ws_size < (size_t)(ws - (char*)d_ws)) return;  // insufficient scratch

  prep_kernel<<<2592, 256, 0, stream>>>(seq, seqb, Wk, Wg, WkT, WgT, q, Wq, qp);
  gemm1_kernel<<<4096, 256, 0, stream>>>(seqb, WkT, qp, bq, bk, alignb);
  gemm2_kernel<<<4096, 256, 0, stream>>>(alignb, WgT, bg, Ws, scores_part);
  context_kernel<<<dim3(32, 1, 16), 256, 0, stream>>>(seqb, scores_part, outW, ctx_part);
  pre_kernel<<<dim3(16, 4), 256, 0, stream>>>(ctx_part, q, Wo, pre_part);
  ln_kernel<<<32, 256, 0, stream>>>(pre_part, q, bo, gamma, beta, outF);
}